// Round 3
// baseline (8072.889 us; speedup 1.0000x reference)
//
#include <hip/hip_runtime.h>
#include <math.h>

#define CDIM 768
#define NHEADS 12
#define DHEAD 64
#define SEQ 577
#define NBATCH 32
#define MTOK (NBATCH*SEQ)      // 18464
#define NIMG 576
#define NMERGE 288
#define GB 8                   // batches per qkv group
#define NGROUP (NBATCH/GB)     // 4
#define MGRP (GB*SEQ)          // 4616 rows per group
#define MLPCH 3456             // MLP chunk rows

// ---- workspace layout (float offsets), peak ~156 MB ----
#define SZ_MC   ((size_t)MTOK*CDIM)              // 14,180,352
#define O_BH    ((size_t)0)                      // h -> x1/x2 (in-place)
#define O_BA    (SZ_MC)                          // att -> h2 -> xn
#define O_BQ    (2*SZ_MC)                        // qkv group -> fc1o chunk -> sim
#define SZ_BQ   ((size_t)GB*SEQ*3*CDIM)          // 10,635,264
#define O_SM    (O_BQ + SZ_BQ)
#define O_MS    (O_SM)
#define O_MASK  (O_SM + (size_t)NBATCH*NIMG)
#define O_POS   (O_MASK + (size_t)NBATCH*NIMG)
#define O_AVG   (O_POS + (size_t)NBATCH*NIMG)
#define O_END   (O_AVG + (size_t)NBATCH*CDIM)
#define NEED_BYTES (O_END * 4)

// ---------------- block reduce (256 threads) ----------------
__device__ __forceinline__ float blk_sum256(float v, float* red) {
    #pragma unroll
    for (int o = 32; o; o >>= 1) v += __shfl_down(v, o);
    if ((threadIdx.x & 63) == 0) red[threadIdx.x >> 6] = v;
    __syncthreads();
    float tot = red[0] + red[1] + red[2] + red[3];
    __syncthreads();
    return tot;
}

// ---------------- LayerNorm: one block per row ----------------
__global__ __launch_bounds__(256) void ln_kernel(const float* __restrict__ x,
        const float* __restrict__ g, const float* __restrict__ b,
        float* __restrict__ out) {
    __shared__ float red[4];
    size_t row = blockIdx.x;
    const float* xr = x + row * CDIM;
    float* orow = out + row * CDIM;
    int t = threadIdx.x;
    float v0 = xr[t], v1 = xr[t + 256], v2 = xr[t + 512];
    float mu = blk_sum256(v0 + v1 + v2, red) * (1.f / CDIM);
    float d0 = v0 - mu, d1 = v1 - mu, d2 = v2 - mu;
    float var = blk_sum256(d0 * d0 + d1 * d1 + d2 * d2, red) * (1.f / CDIM);
    float e = var + 1e-5f;
    float rs = rsqrtf(e);
    rs = rs * (1.5f - 0.5f * e * rs * rs);   // NR refine
    orow[t]       = d0 * rs * g[t]       + b[t];
    orow[t + 256] = d1 * rs * g[t + 256] + b[t + 256];
    orow[t + 512] = d2 * rs * g[t + 512] + b[t + 512];
}

// ---------------- generic fp32 GEMM: C = A(MxK) * B(NxK)^T ----------------
// EPI: 0 = +bias, 1 = +bias+res (res may alias C), 2 = gelu(+bias), 3 = plain
template<int EPI>
__global__ __launch_bounds__(256)
void gemm_bt(const float* __restrict__ A, long long sA, int lda,
             const float* __restrict__ Bm, long long sB, int ldb,
             float* __restrict__ C, long long sC, int ldc,
             const float* __restrict__ bias,
             const float* __restrict__ res,
             int M, int N, int K) {
    __shared__ float As[16][132];
    __shared__ float Bs[16][132];
    int batch = blockIdx.z;
    A  += (size_t)batch * sA;
    Bm += (size_t)batch * sB;
    C  += (size_t)batch * sC;
    const int m0 = blockIdx.x * 128, n0 = blockIdx.y * 128;
    const int t = threadIdx.x;
    const int tx = t & 15, ty = t >> 4;
    float acc[8][8] = {};
    for (int k0 = 0; k0 < K; k0 += 16) {
        #pragma unroll
        for (int i = 0; i < 2; i++) {
            int f = i * 256 + t;          // 0..511
            int mm = f >> 2;              // 0..127
            int k4 = (f & 3) * 4;         // 0,4,8,12
            int row = m0 + mm;
            float4 v = make_float4(0.f, 0.f, 0.f, 0.f);
            if (row < M) v = *(const float4*)(A + (size_t)row * lda + k0 + k4);
            As[k4 + 0][mm] = v.x; As[k4 + 1][mm] = v.y;
            As[k4 + 2][mm] = v.z; As[k4 + 3][mm] = v.w;
            int col = n0 + mm;
            float4 w = make_float4(0.f, 0.f, 0.f, 0.f);
            if (col < N) w = *(const float4*)(Bm + (size_t)col * ldb + k0 + k4);
            Bs[k4 + 0][mm] = w.x; Bs[k4 + 1][mm] = w.y;
            Bs[k4 + 2][mm] = w.z; Bs[k4 + 3][mm] = w.w;
        }
        __syncthreads();
        #pragma unroll
        for (int k = 0; k < 16; k++) {
            float a[8], bb[8];
            *(float4*)(a)      = *(const float4*)&As[k][ty * 4];
            *(float4*)(a + 4)  = *(const float4*)&As[k][64 + ty * 4];
            *(float4*)(bb)     = *(const float4*)&Bs[k][tx * 4];
            *(float4*)(bb + 4) = *(const float4*)&Bs[k][64 + tx * 4];
            #pragma unroll
            for (int i = 0; i < 8; i++)
                #pragma unroll
                for (int j = 0; j < 8; j++)
                    acc[i][j] = fmaf(a[i], bb[j], acc[i][j]);
        }
        __syncthreads();
    }
    #pragma unroll
    for (int i = 0; i < 8; i++) {
        int row = m0 + ((i < 4) ? (ty * 4 + i) : (64 + ty * 4 + i - 4));
        if (row >= M) continue;
        #pragma unroll
        for (int j = 0; j < 8; j++) {
            int col = n0 + ((j < 4) ? (tx * 4 + j) : (64 + tx * 4 + j - 4));
            if (col >= N) continue;
            float v = acc[i][j];
            size_t ci = (size_t)row * ldc + col;
            if (EPI == 0) {
                C[ci] = v + bias[col];
            } else if (EPI == 1) {
                C[ci] = v + bias[col] + res[ci];
            } else if (EPI == 2) {
                v += bias[col];
                C[ci] = 0.5f * v * (1.0f + erff(v * 0.70710678118654752f));
            } else {
                C[ci] = v;
            }
        }
    }
}

// ---------------- fused attention (online softmax) ----------------
// grid: (ceil(SEQ/32), NHEADS, GB), 256 threads; qkv/att are group-local.
__global__ __launch_bounds__(256) void attn_kernel(const float* __restrict__ qkv,
                                                   float* __restrict__ att) {
    const int b = blockIdx.z, h = blockIdx.y, q0 = blockIdx.x * 32;
    const int t = threadIdx.x;
    const int ql = t >> 3;          // 0..31  (q row within tile)
    const int kk = t & 7;           // 0..7
    const int dbase = kk * 8;       // output d slice
    __shared__ float Qs[32][68];
    __shared__ float Ks[64][68];
    __shared__ float Vs[64][68];
    __shared__ float Ss[32][68];
    const size_t rowbase = (size_t)b * SEQ * (3 * CDIM);
    #pragma unroll
    for (int i = 0; i < 2; i++) {
        int f = i * 256 + t;
        int r = f >> 4, d4 = (f & 15) * 4;
        int qrow = q0 + r;
        float4 v = make_float4(0.f, 0.f, 0.f, 0.f);
        if (qrow < SEQ)
            v = *(const float4*)(qkv + rowbase + (size_t)qrow * (3 * CDIM) + h * DHEAD + d4);
        *(float4*)&Qs[r][d4] = v;
    }
    float m_run = -1e30f, l_run = 0.f;
    float acc[8] = {};
    for (int c0 = 0; c0 < SEQ; c0 += 64) {
        __syncthreads();
        #pragma unroll
        for (int i = 0; i < 4; i++) {
            int f = i * 256 + t;
            int r = f >> 4, d4 = (f & 15) * 4;
            int krow = c0 + r;
            float4 kv = make_float4(0.f, 0.f, 0.f, 0.f);
            float4 vv = make_float4(0.f, 0.f, 0.f, 0.f);
            if (krow < SEQ) {
                const float* base = qkv + rowbase + (size_t)krow * (3 * CDIM) + h * DHEAD;
                kv = *(const float4*)(base + CDIM + d4);
                vv = *(const float4*)(base + 2 * CDIM + d4);
            }
            *(float4*)&Ks[r][d4] = kv;
            *(float4*)&Vs[r][d4] = vv;
        }
        __syncthreads();
        #pragma unroll
        for (int j = 0; j < 8; j++) {
            int k = kk + j * 8;
            float sacc = 0.f;
            #pragma unroll
            for (int d = 0; d < 64; d += 4) {
                float4 qv = *(const float4*)&Qs[ql][d];
                float4 kv = *(const float4*)&Ks[k][d];
                sacc = fmaf(qv.x, kv.x, sacc); sacc = fmaf(qv.y, kv.y, sacc);
                sacc = fmaf(qv.z, kv.z, sacc); sacc = fmaf(qv.w, kv.w, sacc);
            }
            Ss[ql][k] = (c0 + k < SEQ) ? sacc * 0.125f : -1e30f;
        }
        __syncthreads();
        float cmax = m_run;
        #pragma unroll 8
        for (int k = 0; k < 64; k++) cmax = fmaxf(cmax, Ss[ql][k]);
        float corr = __expf(m_run - cmax);
        m_run = cmax;
        l_run *= corr;
        #pragma unroll
        for (int j = 0; j < 8; j++) acc[j] *= corr;
        for (int k = 0; k < 64; k++) {
            float p = __expf(Ss[ql][k] - cmax);
            l_run += p;
            float4 v0 = *(const float4*)&Vs[k][dbase];
            float4 v1 = *(const float4*)&Vs[k][dbase + 4];
            acc[0] = fmaf(p, v0.x, acc[0]); acc[1] = fmaf(p, v0.y, acc[1]);
            acc[2] = fmaf(p, v0.z, acc[2]); acc[3] = fmaf(p, v0.w, acc[3]);
            acc[4] = fmaf(p, v1.x, acc[4]); acc[5] = fmaf(p, v1.y, acc[5]);
            acc[6] = fmaf(p, v1.z, acc[6]); acc[7] = fmaf(p, v1.w, acc[7]);
        }
    }
    int qrow = q0 + ql;
    if (qrow < SEQ) {
        float inv = 1.f / l_run;
        float* o = att + ((size_t)b * SEQ + qrow) * CDIM + h * DHEAD + dbase;
        #pragma unroll
        for (int j = 0; j < 8; j++) o[j] = acc[j] * inv;
    }
}

// ---------------- normalize img tokens ----------------
__global__ __launch_bounds__(256) void xn_kernel(const float* __restrict__ x2,
                                                 float* __restrict__ xn) {
    __shared__ float red[4];
    int tok = blockIdx.x;                 // b*576 + n
    int b = tok / NIMG, n = tok % NIMG;
    const float* xr = x2 + ((size_t)b * SEQ + 1 + n) * CDIM;
    float* onr = xn + (size_t)tok * CDIM;
    int t = threadIdx.x;
    float v0 = xr[t], v1 = xr[t + 256], v2 = xr[t + 512];
    float ss = blk_sum256(v0 * v0 + v1 * v1 + v2 * v2, red);
    float nrm = fmaxf(sqrtf(ss), 1e-12f);
    float inv = 1.f / nrm;
    onr[t] = v0 * inv; onr[t + 256] = v1 * inv; onr[t + 512] = v2 * inv;
}

// ---------------- row max of sim (excluding diagonal) ----------------
__global__ __launch_bounds__(64) void rowmax_kernel(const float* __restrict__ sim,
                                                    float* __restrict__ ms) {
    int row = blockIdx.x;                 // b*576 + n
    int b = row / NIMG, n = row % NIMG;
    const float* sr = sim + (size_t)b * NIMG * NIMG + (size_t)n * NIMG;
    int lane = threadIdx.x;
    float mx = -1e30f;
    #pragma unroll
    for (int i = 0; i < NIMG / 64; i++) {
        int m = lane + i * 64;
        if (m != n) mx = fmaxf(mx, sr[m]);
    }
    #pragma unroll
    for (int o = 32; o; o >>= 1) mx = fmaxf(mx, __shfl_down(mx, o));
    if (lane == 0) ms[row] = mx;
}

// ---------------- exact top-k selection with lax.top_k tie semantics ----------------
// merge set = top_k(ms, 288): rank by (value desc, index asc) < 288
// keep  set = top_k(-ms, 288): rank by (value asc, index asc) < 288
// NOTE: with ties straddling the boundary these sets OVERLAP (lower-index
// member in both) and the higher-index member is in NEITHER — must match.
__global__ __launch_bounds__(576) void select_kernel(const float* __restrict__ ms,
        int* __restrict__ mergemask, int* __restrict__ keeppos) {
    __shared__ float v[NIMG];
    __shared__ int keepf[NIMG];
    int b = blockIdx.x;
    int n = threadIdx.x;
    v[n] = ms[b * NIMG + n];
    __syncthreads();
    float vn = v[n];
    int rank_desc = 0, rank_asc = 0;
    for (int m = 0; m < NIMG; m++) {
        float vm = v[m];
        int tie_lo = (vm == vn && m < n);
        rank_desc += (vm > vn) || tie_lo;
        rank_asc  += (vm < vn) || tie_lo;
    }
    int merge = rank_desc < NMERGE;
    int keep  = rank_asc  < NMERGE;
    mergemask[b * NIMG + n] = merge;
    keepf[n] = keep;
    __syncthreads();
    if (keep) {
        int pos = 0;
        for (int m = 0; m < n; m++) pos += keepf[m];
        keeppos[b * NIMG + n] = pos;
    } else {
        keeppos[b * NIMG + n] = -1;
    }
}

// ---------------- average of merged tokens ----------------
__global__ __launch_bounds__(256) void avg_kernel(const float* __restrict__ x2,
        const int* __restrict__ mask, float* __restrict__ avg) {
    int b = blockIdx.x;
    int t = threadIdx.x;
    #pragma unroll
    for (int cc = 0; cc < 3; cc++) {
        int c = t + cc * 256;
        float s = 0.f;
        for (int n = 0; n < NIMG; n++)
            if (mask[b * NIMG + n]) s += x2[((size_t)b * SEQ + 1 + n) * CDIM + c];
        avg[b * CDIM + c] = (s / (float)NMERGE) / (float)(NIMG - NMERGE);
    }
}

// ---------------- assemble output ----------------
__global__ __launch_bounds__(192) void assemble_kernel(const float* __restrict__ x2,
        const int* __restrict__ keeppos, const float* __restrict__ avg,
        float* __restrict__ out) {
    int g = blockIdx.x;                   // b*577 + s
    int b = g / SEQ, s_ = g % SEQ;
    int t = threadIdx.x;                  // 192 float4 lanes
    const float4* src = (const float4*)(x2 + (size_t)g * CDIM);
    if (s_ == 0) {
        float4* dst = (float4*)(out + (size_t)b * 289 * CDIM);
        dst[t] = src[t];
    } else {
        int n = s_ - 1;
        int pos = keeppos[b * NIMG + n];
        if (pos < 0) return;
        const float4* av = (const float4*)(avg + (size_t)b * CDIM);
        float4 v = src[t], a = av[t];
        v.x += a.x; v.y += a.y; v.z += a.z; v.w += a.w;
        float4* dst = (float4*)(out + ((size_t)b * 289 + 1 + pos) * CDIM);
        dst[t] = v;
    }
}

extern "C" void kernel_launch(void* const* d_in, const int* in_sizes, int n_in,
                              void* d_out, int out_size, void* d_ws, size_t ws_size,
                              hipStream_t stream) {
    const float* x      = (const float*)d_in[0];
    const float* qkv_w  = (const float*)d_in[1];
    const float* qkv_b  = (const float*)d_in[2];
    const float* proj_w = (const float*)d_in[3];
    const float* proj_b = (const float*)d_in[4];
    const float* ln1_g  = (const float*)d_in[5];
    const float* ln1_b  = (const float*)d_in[6];
    const float* ln2_g  = (const float*)d_in[7];
    const float* ln2_b  = (const float*)d_in[8];
    const float* fc1_w  = (const float*)d_in[9];
    const float* fc1_b  = (const float*)d_in[10];
    const float* fc2_w  = (const float*)d_in[11];
    const float* fc2_b  = (const float*)d_in[12];

    if (ws_size < NEED_BYTES) return;   // diagnostic: clean fail instead of fault

    float* ws   = (float*)d_ws;
    float* bh   = ws + O_BH;    // h -> x1/x2 (in-place)
    float* ba   = ws + O_BA;    // att -> h2 -> xn
    float* bq   = ws + O_BQ;    // qkv group -> fc1o chunk -> sim
    float* ms   = ws + O_MS;
    int*   mask = (int*)(ws + O_MASK);
    int*   pos  = (int*)(ws + O_POS);
    float* avg  = ws + O_AVG;
    float* outp = (float*)d_out;

    // 1. h = LN1(x)
    ln_kernel<<<MTOK, 256, 0, stream>>>(x, ln1_g, ln1_b, bh);

    // 2. per-group qkv GEMM + attention (BQ reused per group; stream-serialized)
    for (int g = 0; g < NGROUP; g++) {
        const float* hg = bh + (size_t)g * MGRP * CDIM;
        float* attg = ba + (size_t)g * MGRP * CDIM;
        gemm_bt<0><<<dim3((MGRP + 127) / 128, 18, 1), 256, 0, stream>>>(
            hg, 0, CDIM, qkv_w, 0, CDIM, bq, 0, 3 * CDIM, qkv_b, nullptr,
            MGRP, 3 * CDIM, CDIM);
        attn_kernel<<<dim3((SEQ + 31) / 32, NHEADS, GB), 256, 0, stream>>>(bq, attg);
    }

    // 3. x1 = x + att @ proj_w^T + proj_b   (x1 -> BH; h dead)
    gemm_bt<1><<<dim3((MTOK + 127) / 128, 6, 1), 256, 0, stream>>>(
        ba, 0, CDIM, proj_w, 0, CDIM, bh, 0, CDIM, proj_b, x, MTOK, CDIM, CDIM);

    // 4. h2 = LN2(x1)  (h2 -> BA; att dead)
    ln_kernel<<<MTOK, 256, 0, stream>>>(bh, ln2_g, ln2_b, ba);

    // 5. MLP in M-chunks; fc1o chunk in BQ; x2 = x1 + mlp in-place in BH
    for (int c0 = 0; c0 < MTOK; c0 += MLPCH) {
        int mc = (MTOK - c0 < MLPCH) ? (MTOK - c0) : MLPCH;
        const float* h2c = ba + (size_t)c0 * CDIM;
        float* x1c = bh + (size_t)c0 * CDIM;
        gemm_bt<2><<<dim3((mc + 127) / 128, 24, 1), 256, 0, stream>>>(
            h2c, 0, CDIM, fc1_w, 0, CDIM, bq, 0, 3072, fc1_b, nullptr,
            mc, 3072, CDIM);
        gemm_bt<1><<<dim3((mc + 127) / 128, 6, 1), 256, 0, stream>>>(
            bq, 0, 3072, fc2_w, 0, 3072, x1c, 0, CDIM, fc2_b, x1c,
            mc, CDIM, 3072);
    }

    // 6. normalize img tokens (xn -> BA; h2 dead)
    xn_kernel<<<NBATCH * NIMG, 256, 0, stream>>>(bh, ba);

    // 7. sim = xn @ xn^T per batch (sim -> BQ; fc1o dead)
    gemm_bt<3><<<dim3(5, 5, NBATCH), 256, 0, stream>>>(
        ba, (long long)NIMG * CDIM, CDIM, ba, (long long)NIMG * CDIM, CDIM,
        bq, (long long)NIMG * NIMG, NIMG, nullptr, nullptr, NIMG, NIMG, CDIM);

    // 8. row max (excl diag)
    rowmax_kernel<<<NBATCH * NIMG, 64, 0, stream>>>(bq, ms);
    // 9. top-k selection with exact lax.top_k tie semantics
    select_kernel<<<NBATCH, NIMG, 0, stream>>>(ms, mask, pos);
    // 10. merged-token average
    avg_kernel<<<NBATCH, 256, 0, stream>>>(bh, mask, avg);
    // 11. assemble output [cls | keep + avg/num_keep]
    assemble_kernel<<<MTOK, 192, 0, stream>>>(bh, pos, avg, outp);
}

// Round 4
// 4816.871 us; speedup vs baseline: 1.6760x; 1.6760x over previous
//
#include <hip/hip_runtime.h>
#include <math.h>

#define CDIM 768
#define NHEADS 12
#define DHEAD 64
#define SEQ 577
#define NBATCH 32
#define MTOK (NBATCH*SEQ)      // 18464
#define NIMG 576
#define NMERGE 288
#define GB 8                   // batches per qkv group
#define NGROUP (NBATCH/GB)     // 4
#define MGRP (GB*SEQ)          // 4616 rows per group
#define MLPCH 3456             // MLP chunk rows

// ---- workspace layout (float offsets), peak ~156 MB ----
#define SZ_MC   ((size_t)MTOK*CDIM)              // 14,180,352
#define O_BH    ((size_t)0)                      // h -> x1/x2 (in-place)
#define O_BA    (SZ_MC)                          // att -> h2 -> xn
#define O_BQ    (2*SZ_MC)                        // qkv group -> fc1o chunk -> sim
#define SZ_BQ   ((size_t)GB*SEQ*3*CDIM)          // 10,635,264
#define O_SM    (O_BQ + SZ_BQ)
#define O_MS    (O_SM)
#define O_MASK  (O_SM + (size_t)NBATCH*NIMG)
#define O_POS   (O_MASK + (size_t)NBATCH*NIMG)
#define O_AVG   (O_POS + (size_t)NBATCH*NIMG)
#define O_END   (O_AVG + (size_t)NBATCH*CDIM)
#define NEED_BYTES (O_END * 4)

typedef __attribute__((ext_vector_type(8))) short bf16x8;
typedef __attribute__((ext_vector_type(4))) float f32x4;

__device__ __forceinline__ unsigned short f2bf(float f) {
    unsigned int u = __float_as_uint(f);
    u += 0x7fff + ((u >> 16) & 1);           // RNE
    return (unsigned short)(u >> 16);
}
__device__ __forceinline__ float bf2f(unsigned short h) {
    return __uint_as_float(((unsigned int)h) << 16);
}

// ---------------- block reduce (256 threads) ----------------
__device__ __forceinline__ float blk_sum256(float v, float* red) {
    #pragma unroll
    for (int o = 32; o; o >>= 1) v += __shfl_down(v, o);
    if ((threadIdx.x & 63) == 0) red[threadIdx.x >> 6] = v;
    __syncthreads();
    float tot = red[0] + red[1] + red[2] + red[3];
    __syncthreads();
    return tot;
}

// ---------------- LayerNorm: one block per row ----------------
__global__ __launch_bounds__(256) void ln_kernel(const float* __restrict__ x,
        const float* __restrict__ g, const float* __restrict__ b,
        float* __restrict__ out) {
    __shared__ float red[4];
    size_t row = blockIdx.x;
    const float* xr = x + row * CDIM;
    float* orow = out + row * CDIM;
    int t = threadIdx.x;
    float v0 = xr[t], v1 = xr[t + 256], v2 = xr[t + 512];
    float mu = blk_sum256(v0 + v1 + v2, red) * (1.f / CDIM);
    float d0 = v0 - mu, d1 = v1 - mu, d2 = v2 - mu;
    float var = blk_sum256(d0 * d0 + d1 * d1 + d2 * d2, red) * (1.f / CDIM);
    float e = var + 1e-5f;
    float rs = rsqrtf(e);
    rs = rs * (1.5f - 0.5f * e * rs * rs);   // NR refine
    orow[t]       = d0 * rs * g[t]       + b[t];
    orow[t + 256] = d1 * rs * g[t + 256] + b[t + 256];
    orow[t + 512] = d2 * rs * g[t + 512] + b[t + 512];
}

// ---------------- MFMA bf16x3-split GEMM: C = A(MxK) * B(NxK)^T ----------------
// fp32-equivalent accuracy: A=Ah+Al, B=Bh+Bl (bf16), C ~= AhBh + AhBl + AlBh.
// 128x128 tile, BK=32, 4 waves (2x2), 16x16x32 MFMA.
// LDS row layout (128B): [hi k0..31 | lo k0..31], swizzle byte ^= (row&7)<<4.
// OOB rows/cols clamp to last row (garbage only reaches never-stored outputs).
// EPI: 0 = +bias, 1 = +bias+res (res may alias C), 2 = gelu(+bias), 3 = plain
template<int EPI>
__global__ __launch_bounds__(256)
void gemm_mfma(const float* __restrict__ A, long long sA, int lda,
               const float* __restrict__ Bm, long long sB, int ldb,
               float* __restrict__ C, long long sC, int ldc,
               const float* __restrict__ bias,
               const float* __restrict__ res,
               int M, int N, int K) {
    __shared__ unsigned short Asl[128 * 64];
    __shared__ unsigned short Bsl[128 * 64];
    int batch = blockIdx.z;
    A  += (size_t)batch * sA;
    Bm += (size_t)batch * sB;
    C  += (size_t)batch * sC;
    const int m0 = blockIdx.x * 128, n0 = blockIdx.y * 128;
    const int t = threadIdx.x;
    const int lane = t & 63, wid = t >> 6;
    const int wr = wid >> 1, wc = wid & 1;       // wave 2x2 -> 64x64 sub-tile
    const int srow = t >> 3;                     // staging row 0..31
    const int sj   = t & 7;                      // staging k-chunk (4 fp32)

    f32x4 acc[4][4];
    #pragma unroll
    for (int i = 0; i < 4; i++)
        #pragma unroll
        for (int j = 0; j < 4; j++) {
            f32x4 z = {0.f, 0.f, 0.f, 0.f};
            acc[i][j] = z;
        }

    const int nsteps = K >> 5;
    for (int ks = 0; ks < nsteps; ks++) {
        const int k0 = ks << 5;
        // ---- global loads (issued before barrier: overlap w/ prev MFMA) ----
        float4 va[4], vb[4];
        #pragma unroll
        for (int i = 0; i < 4; i++) {
            int r = srow + i * 32;
            int ra = m0 + r; ra = ra < M ? ra : M - 1;
            int rb = n0 + r; rb = rb < N ? rb : N - 1;
            va[i] = *(const float4*)(A  + (size_t)ra * lda + k0 + sj * 4);
            vb[i] = *(const float4*)(Bm + (size_t)rb * ldb + k0 + sj * 4);
        }
        __syncthreads();   // previous step's LDS reads complete
        // ---- convert fp32 -> (hi, lo) bf16 and write LDS ----
        #pragma unroll
        for (int i = 0; i < 4; i++) {
            int r = srow + i * 32;
            int swz = (r & 7) << 4;
            float aa[4] = {va[i].x, va[i].y, va[i].z, va[i].w};
            float bb[4] = {vb[i].x, vb[i].y, vb[i].z, vb[i].w};
            ushort4 ahv, alv, bhv, blv;
            {
                unsigned short h0 = f2bf(aa[0]), h1 = f2bf(aa[1]), h2 = f2bf(aa[2]), h3 = f2bf(aa[3]);
                ahv = make_ushort4(h0, h1, h2, h3);
                alv = make_ushort4(f2bf(aa[0] - bf2f(h0)), f2bf(aa[1] - bf2f(h1)),
                                   f2bf(aa[2] - bf2f(h2)), f2bf(aa[3] - bf2f(h3)));
                unsigned short g0 = f2bf(bb[0]), g1 = f2bf(bb[1]), g2 = f2bf(bb[2]), g3 = f2bf(bb[3]);
                bhv = make_ushort4(g0, g1, g2, g3);
                blv = make_ushort4(f2bf(bb[0] - bf2f(g0)), f2bf(bb[1] - bf2f(g1)),
                                   f2bf(bb[2] - bf2f(g2)), f2bf(bb[3] - bf2f(g3)));
            }
            int ohi = ((8 * sj) ^ swz) >> 1;         // ushort index within row
            int olo = ((64 + 8 * sj) ^ swz) >> 1;
            *(ushort4*)&Asl[r * 64 + ohi] = ahv;
            *(ushort4*)&Asl[r * 64 + olo] = alv;
            *(ushort4*)&Bsl[r * 64 + ohi] = bhv;
            *(ushort4*)&Bsl[r * 64 + olo] = blv;
        }
        __syncthreads();
        // ---- fragment loads + 48 MFMA ----
        const int fr = lane & 15, kg = lane >> 4;
        bf16x8 ah[4], al[4], bh[4], bl[4];
        #pragma unroll
        for (int m = 0; m < 4; m++) {
            int r = wr * 64 + m * 16 + fr;
            int swz = (r & 7) << 4;
            const unsigned char* base = (const unsigned char*)&Asl[r * 64];
            ah[m] = *(const bf16x8*)(base + ((16 * kg) ^ swz));
            al[m] = *(const bf16x8*)(base + ((64 + 16 * kg) ^ swz));
        }
        #pragma unroll
        for (int n = 0; n < 4; n++) {
            int r = wc * 64 + n * 16 + fr;
            int swz = (r & 7) << 4;
            const unsigned char* base = (const unsigned char*)&Bsl[r * 64];
            bh[n] = *(const bf16x8*)(base + ((16 * kg) ^ swz));
            bl[n] = *(const bf16x8*)(base + ((64 + 16 * kg) ^ swz));
        }
        #pragma unroll
        for (int m = 0; m < 4; m++)
            #pragma unroll
            for (int n = 0; n < 4; n++) {
                acc[m][n] = __builtin_amdgcn_mfma_f32_16x16x32_bf16(ah[m], bh[n], acc[m][n], 0, 0, 0);
                acc[m][n] = __builtin_amdgcn_mfma_f32_16x16x32_bf16(ah[m], bl[n], acc[m][n], 0, 0, 0);
                acc[m][n] = __builtin_amdgcn_mfma_f32_16x16x32_bf16(al[m], bh[n], acc[m][n], 0, 0, 0);
            }
    }

    // ---- epilogue: C/D layout col=lane&15, row=(lane>>4)*4+reg ----
    const int fr = lane & 15, fq = lane >> 4;
    #pragma unroll
    for (int m = 0; m < 4; m++) {
        #pragma unroll
        for (int rr = 0; rr < 4; rr++) {
            int row = m0 + wr * 64 + m * 16 + fq * 4 + rr;
            if (row >= M) continue;
            #pragma unroll
            for (int n = 0; n < 4; n++) {
                int col = n0 + wc * 64 + n * 16 + fr;
                if (col >= N) continue;
                float v = acc[m][n][rr];
                size_t ci = (size_t)row * ldc + col;
                if (EPI == 0) {
                    C[ci] = v + bias[col];
                } else if (EPI == 1) {
                    C[ci] = v + bias[col] + res[ci];
                } else if (EPI == 2) {
                    v += bias[col];
                    C[ci] = 0.5f * v * (1.0f + erff(v * 0.70710678118654752f));
                } else {
                    C[ci] = v;
                }
            }
        }
    }
}

// ---------------- fused attention (online softmax) ----------------
__global__ __launch_bounds__(256) void attn_kernel(const float* __restrict__ qkv,
                                                   float* __restrict__ att) {
    const int b = blockIdx.z, h = blockIdx.y, q0 = blockIdx.x * 32;
    const int t = threadIdx.x;
    const int ql = t >> 3;          // 0..31  (q row within tile)
    const int kk = t & 7;           // 0..7
    const int dbase = kk * 8;       // output d slice
    __shared__ float Qs[32][68];
    __shared__ float Ks[64][68];
    __shared__ float Vs[64][68];
    __shared__ float Ss[32][68];
    const size_t rowbase = (size_t)b * SEQ * (3 * CDIM);
    #pragma unroll
    for (int i = 0; i < 2; i++) {
        int f = i * 256 + t;
        int r = f >> 4, d4 = (f & 15) * 4;
        int qrow = q0 + r;
        float4 v = make_float4(0.f, 0.f, 0.f, 0.f);
        if (qrow < SEQ)
            v = *(const float4*)(qkv + rowbase + (size_t)qrow * (3 * CDIM) + h * DHEAD + d4);
        *(float4*)&Qs[r][d4] = v;
    }
    float m_run = -1e30f, l_run = 0.f;
    float acc[8] = {};
    for (int c0 = 0; c0 < SEQ; c0 += 64) {
        __syncthreads();
        #pragma unroll
        for (int i = 0; i < 4; i++) {
            int f = i * 256 + t;
            int r = f >> 4, d4 = (f & 15) * 4;
            int krow = c0 + r;
            float4 kv = make_float4(0.f, 0.f, 0.f, 0.f);
            float4 vv = make_float4(0.f, 0.f, 0.f, 0.f);
            if (krow < SEQ) {
                const float* base = qkv + rowbase + (size_t)krow * (3 * CDIM) + h * DHEAD;
                kv = *(const float4*)(base + CDIM + d4);
                vv = *(const float4*)(base + 2 * CDIM + d4);
            }
            *(float4*)&Ks[r][d4] = kv;
            *(float4*)&Vs[r][d4] = vv;
        }
        __syncthreads();
        #pragma unroll
        for (int j = 0; j < 8; j++) {
            int k = kk + j * 8;
            float sacc = 0.f;
            #pragma unroll
            for (int d = 0; d < 64; d += 4) {
                float4 qv = *(const float4*)&Qs[ql][d];
                float4 kv = *(const float4*)&Ks[k][d];
                sacc = fmaf(qv.x, kv.x, sacc); sacc = fmaf(qv.y, kv.y, sacc);
                sacc = fmaf(qv.z, kv.z, sacc); sacc = fmaf(qv.w, kv.w, sacc);
            }
            Ss[ql][k] = (c0 + k < SEQ) ? sacc * 0.125f : -1e30f;
        }
        __syncthreads();
        float cmax = m_run;
        #pragma unroll 8
        for (int k = 0; k < 64; k++) cmax = fmaxf(cmax, Ss[ql][k]);
        float corr = __expf(m_run - cmax);
        m_run = cmax;
        l_run *= corr;
        #pragma unroll
        for (int j = 0; j < 8; j++) acc[j] *= corr;
        for (int k = 0; k < 64; k++) {
            float p = __expf(Ss[ql][k] - cmax);
            l_run += p;
            float4 v0 = *(const float4*)&Vs[k][dbase];
            float4 v1 = *(const float4*)&Vs[k][dbase + 4];
            acc[0] = fmaf(p, v0.x, acc[0]); acc[1] = fmaf(p, v0.y, acc[1]);
            acc[2] = fmaf(p, v0.z, acc[2]); acc[3] = fmaf(p, v0.w, acc[3]);
            acc[4] = fmaf(p, v1.x, acc[4]); acc[5] = fmaf(p, v1.y, acc[5]);
            acc[6] = fmaf(p, v1.z, acc[6]); acc[7] = fmaf(p, v1.w, acc[7]);
        }
    }
    int qrow = q0 + ql;
    if (qrow < SEQ) {
        float inv = 1.f / l_run;
        float* o = att + ((size_t)b * SEQ + qrow) * CDIM + h * DHEAD + dbase;
        #pragma unroll
        for (int j = 0; j < 8; j++) o[j] = acc[j] * inv;
    }
}

// ---------------- normalize img tokens ----------------
__global__ __launch_bounds__(256) void xn_kernel(const float* __restrict__ x2,
                                                 float* __restrict__ xn) {
    __shared__ float red[4];
    int tok = blockIdx.x;
    int b = tok / NIMG, n = tok % NIMG;
    const float* xr = x2 + ((size_t)b * SEQ + 1 + n) * CDIM;
    float* onr = xn + (size_t)tok * CDIM;
    int t = threadIdx.x;
    float v0 = xr[t], v1 = xr[t + 256], v2 = xr[t + 512];
    float ss = blk_sum256(v0 * v0 + v1 * v1 + v2 * v2, red);
    float nrm = fmaxf(sqrtf(ss), 1e-12f);
    float inv = 1.f / nrm;
    onr[t] = v0 * inv; onr[t + 256] = v1 * inv; onr[t + 512] = v2 * inv;
}

// ---------------- row max of symmetrized sim (excluding diagonal) ----------------
// max over 0.5*(sim + sim^T): bitwise-symmetric (restores exact tie structure
// that the MFMA 3-product add order would otherwise break by ~1 ulp).
__global__ __launch_bounds__(64) void rowmax_kernel(const float* __restrict__ sim,
                                                    float* __restrict__ ms) {
    int row = blockIdx.x;
    int b = row / NIMG, n = row % NIMG;
    const float* sb = sim + (size_t)b * NIMG * NIMG;
    int lane = threadIdx.x;
    float mx = -1e30f;
    #pragma unroll
    for (int i = 0; i < NIMG / 64; i++) {
        int m = lane + i * 64;
        if (m != n) {
            float v = 0.5f * (sb[(size_t)n * NIMG + m] + sb[(size_t)m * NIMG + n]);
            mx = fmaxf(mx, v);
        }
    }
    #pragma unroll
    for (int o = 32; o; o >>= 1) mx = fmaxf(mx, __shfl_down(mx, o));
    if (lane == 0) ms[row] = mx;
}

// ---------------- exact top-k selection with lax.top_k tie semantics ----------------
__global__ __launch_bounds__(576) void select_kernel(const float* __restrict__ ms,
        int* __restrict__ mergemask, int* __restrict__ keeppos) {
    __shared__ float v[NIMG];
    __shared__ int keepf[NIMG];
    int b = blockIdx.x;
    int n = threadIdx.x;
    v[n] = ms[b * NIMG + n];
    __syncthreads();
    float vn = v[n];
    int rank_desc = 0, rank_asc = 0;
    for (int m = 0; m < NIMG; m++) {
        float vm = v[m];
        int tie_lo = (vm == vn && m < n);
        rank_desc += (vm > vn) || tie_lo;
        rank_asc  += (vm < vn) || tie_lo;
    }
    int merge = rank_desc < NMERGE;
    int keep  = rank_asc  < NMERGE;
    mergemask[b * NIMG + n] = merge;
    keepf[n] = keep;
    __syncthreads();
    if (keep) {
        int pos = 0;
        for (int m = 0; m < n; m++) pos += keepf[m];
        keeppos[b * NIMG + n] = pos;
    } else {
        keeppos[b * NIMG + n] = -1;
    }
}

// ---------------- average of merged tokens ----------------
__global__ __launch_bounds__(256) void avg_kernel(const float* __restrict__ x2,
        const int* __restrict__ mask, float* __restrict__ avg) {
    int b = blockIdx.x;
    int t = threadIdx.x;
    #pragma unroll
    for (int cc = 0; cc < 3; cc++) {
        int c = t + cc * 256;
        float s = 0.f;
        for (int n = 0; n < NIMG; n++)
            if (mask[b * NIMG + n]) s += x2[((size_t)b * SEQ + 1 + n) * CDIM + c];
        avg[b * CDIM + c] = (s / (float)NMERGE) / (float)(NIMG - NMERGE);
    }
}

// ---------------- assemble output ----------------
__global__ __launch_bounds__(192) void assemble_kernel(const float* __restrict__ x2,
        const int* __restrict__ keeppos, const float* __restrict__ avg,
        float* __restrict__ out) {
    int g = blockIdx.x;
    int b = g / SEQ, s_ = g % SEQ;
    int t = threadIdx.x;
    const float4* src = (const float4*)(x2 + (size_t)g * CDIM);
    if (s_ == 0) {
        float4* dst = (float4*)(out + (size_t)b * 289 * CDIM);
        dst[t] = src[t];
    } else {
        int n = s_ - 1;
        int pos = keeppos[b * NIMG + n];
        if (pos < 0) return;
        const float4* av = (const float4*)(avg + (size_t)b * CDIM);
        float4 v = src[t], a = av[t];
        v.x += a.x; v.y += a.y; v.z += a.z; v.w += a.w;
        float4* dst = (float4*)(out + ((size_t)b * 289 + 1 + pos) * CDIM);
        dst[t] = v;
    }
}

extern "C" void kernel_launch(void* const* d_in, const int* in_sizes, int n_in,
                              void* d_out, int out_size, void* d_ws, size_t ws_size,
                              hipStream_t stream) {
    const float* x      = (const float*)d_in[0];
    const float* qkv_w  = (const float*)d_in[1];
    const float* qkv_b  = (const float*)d_in[2];
    const float* proj_w = (const float*)d_in[3];
    const float* proj_b = (const float*)d_in[4];
    const float* ln1_g  = (const float*)d_in[5];
    const float* ln1_b  = (const float*)d_in[6];
    const float* ln2_g  = (const float*)d_in[7];
    const float* ln2_b  = (const float*)d_in[8];
    const float* fc1_w  = (const float*)d_in[9];
    const float* fc1_b  = (const float*)d_in[10];
    const float* fc2_w  = (const float*)d_in[11];
    const float* fc2_b  = (const float*)d_in[12];

    if (ws_size < NEED_BYTES) return;

    float* ws   = (float*)d_ws;
    float* bh   = ws + O_BH;    // h -> x1/x2 (in-place)
    float* ba   = ws + O_BA;    // att -> h2 -> xn
    float* bq   = ws + O_BQ;    // qkv group -> fc1o chunk -> sim
    float* ms   = ws + O_MS;
    int*   mask = (int*)(ws + O_MASK);
    int*   pos  = (int*)(ws + O_POS);
    float* avg  = ws + O_AVG;
    float* outp = (float*)d_out;

    // 1. h = LN1(x)
    ln_kernel<<<MTOK, 256, 0, stream>>>(x, ln1_g, ln1_b, bh);

    // 2. per-group qkv GEMM + attention
    for (int g = 0; g < NGROUP; g++) {
        const float* hg = bh + (size_t)g * MGRP * CDIM;
        float* attg = ba + (size_t)g * MGRP * CDIM;
        gemm_mfma<0><<<dim3((MGRP + 127) / 128, 18, 1), 256, 0, stream>>>(
            hg, 0, CDIM, qkv_w, 0, CDIM, bq, 0, 3 * CDIM, qkv_b, nullptr,
            MGRP, 3 * CDIM, CDIM);
        attn_kernel<<<dim3((SEQ + 31) / 32, NHEADS, GB), 256, 0, stream>>>(bq, attg);
    }

    // 3. x1 = x + att @ proj_w^T + proj_b
    gemm_mfma<1><<<dim3((MTOK + 127) / 128, 6, 1), 256, 0, stream>>>(
        ba, 0, CDIM, proj_w, 0, CDIM, bh, 0, CDIM, proj_b, x, MTOK, CDIM, CDIM);

    // 4. h2 = LN2(x1)
    ln_kernel<<<MTOK, 256, 0, stream>>>(bh, ln2_g, ln2_b, ba);

    // 5. MLP in M-chunks
    for (int c0 = 0; c0 < MTOK; c0 += MLPCH) {
        int mc = (MTOK - c0 < MLPCH) ? (MTOK - c0) : MLPCH;
        const float* h2c = ba + (size_t)c0 * CDIM;
        float* x1c = bh + (size_t)c0 * CDIM;
        gemm_mfma<2><<<dim3((mc + 127) / 128, 24, 1), 256, 0, stream>>>(
            h2c, 0, CDIM, fc1_w, 0, CDIM, bq, 0, 3072, fc1_b, nullptr,
            mc, 3072, CDIM);
        gemm_mfma<1><<<dim3((mc + 127) / 128, 6, 1), 256, 0, stream>>>(
            bq, 0, 3072, fc2_w, 0, 3072, x1c, 0, CDIM, fc2_b, x1c,
            mc, CDIM, 3072);
    }

    // 6. normalize img tokens
    xn_kernel<<<NBATCH * NIMG, 256, 0, stream>>>(bh, ba);

    // 7. sim = xn @ xn^T per batch
    gemm_mfma<3><<<dim3(5, 5, NBATCH), 256, 0, stream>>>(
        ba, (long long)NIMG * CDIM, CDIM, ba, (long long)NIMG * CDIM, CDIM,
        bq, (long long)NIMG * NIMG, NIMG, nullptr, nullptr, NIMG, NIMG, CDIM);

    // 8. row max of symmetrized sim
    rowmax_kernel<<<NBATCH * NIMG, 64, 0, stream>>>(bq, ms);
    // 9. top-k selection
    select_kernel<<<NBATCH, NIMG, 0, stream>>>(ms, mask, pos);
    // 10. merged-token average
    avg_kernel<<<NBATCH, 256, 0, stream>>>(bh, mask, avg);
    // 11. assemble output
    assemble_kernel<<<MTOK, 192, 0, stream>>>(bh, pos, avg, outp);
}

// Round 5
// 3453.962 us; speedup vs baseline: 2.3373x; 1.3946x over previous
//
#include <hip/hip_runtime.h>
#include <math.h>

#define CDIM 768
#define NHEADS 12
#define DHEAD 64
#define SEQ 577
#define NBATCH 32
#define MTOK (NBATCH*SEQ)      // 18464
#define NIMG 576
#define NMERGE 288
#define GB 8                   // batches per qkv group
#define NGROUP (NBATCH/GB)     // 4
#define MGRP (GB*SEQ)          // 4616 rows per group
#define MLPCH 3456             // MLP chunk rows

// ---- workspace layout (float offsets), peak ~156 MB ----
#define SZ_MC   ((size_t)MTOK*CDIM)              // 14,180,352
#define O_BH    ((size_t)0)                      // h -> x1/x2 (in-place)
#define O_BA    (SZ_MC)                          // att -> h2 -> xn
#define O_BQ    (2*SZ_MC)                        // qkv group -> fc1o chunk -> sim
#define SZ_BQ   ((size_t)GB*SEQ*3*CDIM)          // 10,635,264
#define O_SM    (O_BQ + SZ_BQ)
#define O_MS    (O_SM)
#define O_MASK  (O_SM + (size_t)NBATCH*NIMG)
#define O_POS   (O_MASK + (size_t)NBATCH*NIMG)
#define O_AVG   (O_POS + (size_t)NBATCH*NIMG)
#define O_END   (O_AVG + (size_t)NBATCH*CDIM)
#define NEED_BYTES (O_END * 4)

typedef __attribute__((ext_vector_type(8))) short bf16x8;
typedef __attribute__((ext_vector_type(4))) float f32x4;

__device__ __forceinline__ unsigned short f2bf(float f) {
    unsigned int u = __float_as_uint(f);
    u += 0x7fff + ((u >> 16) & 1);           // RNE
    return (unsigned short)(u >> 16);
}
__device__ __forceinline__ float bf2f(unsigned short h) {
    return __uint_as_float(((unsigned int)h) << 16);
}

// ---------------- block reduce (256 threads) ----------------
__device__ __forceinline__ float blk_sum256(float v, float* red) {
    #pragma unroll
    for (int o = 32; o; o >>= 1) v += __shfl_down(v, o);
    if ((threadIdx.x & 63) == 0) red[threadIdx.x >> 6] = v;
    __syncthreads();
    float tot = red[0] + red[1] + red[2] + red[3];
    __syncthreads();
    return tot;
}

// ---------------- LayerNorm: one block per row ----------------
__global__ __launch_bounds__(256) void ln_kernel(const float* __restrict__ x,
        const float* __restrict__ g, const float* __restrict__ b,
        float* __restrict__ out) {
    __shared__ float red[4];
    size_t row = blockIdx.x;
    const float* xr = x + row * CDIM;
    float* orow = out + row * CDIM;
    int t = threadIdx.x;
    float v0 = xr[t], v1 = xr[t + 256], v2 = xr[t + 512];
    float mu = blk_sum256(v0 + v1 + v2, red) * (1.f / CDIM);
    float d0 = v0 - mu, d1 = v1 - mu, d2 = v2 - mu;
    float var = blk_sum256(d0 * d0 + d1 * d1 + d2 * d2, red) * (1.f / CDIM);
    float e = var + 1e-5f;
    float rs = rsqrtf(e);
    rs = rs * (1.5f - 0.5f * e * rs * rs);   // NR refine
    orow[t]       = d0 * rs * g[t]       + b[t];
    orow[t + 256] = d1 * rs * g[t + 256] + b[t + 256];
    orow[t + 512] = d2 * rs * g[t + 512] + b[t + 512];
}

// ---------------- MFMA bf16x3-split GEMM: C = A(MxK) * B(NxK)^T ----------------
template<int EPI>
__global__ __launch_bounds__(256)
void gemm_mfma(const float* __restrict__ A, long long sA, int lda,
               const float* __restrict__ Bm, long long sB, int ldb,
               float* __restrict__ C, long long sC, int ldc,
               const float* __restrict__ bias,
               const float* __restrict__ res,
               int M, int N, int K) {
    __shared__ unsigned short Asl[128 * 64];
    __shared__ unsigned short Bsl[128 * 64];
    int batch = blockIdx.z;
    A  += (size_t)batch * sA;
    Bm += (size_t)batch * sB;
    C  += (size_t)batch * sC;
    const int m0 = blockIdx.x * 128, n0 = blockIdx.y * 128;
    const int t = threadIdx.x;
    const int lane = t & 63, wid = t >> 6;
    const int wr = wid >> 1, wc = wid & 1;
    const int srow = t >> 3;
    const int sj   = t & 7;

    f32x4 acc[4][4];
    #pragma unroll
    for (int i = 0; i < 4; i++)
        #pragma unroll
        for (int j = 0; j < 4; j++) {
            f32x4 z = {0.f, 0.f, 0.f, 0.f};
            acc[i][j] = z;
        }

    const int nsteps = K >> 5;
    for (int ks = 0; ks < nsteps; ks++) {
        const int k0 = ks << 5;
        float4 va[4], vb[4];
        #pragma unroll
        for (int i = 0; i < 4; i++) {
            int r = srow + i * 32;
            int ra = m0 + r; ra = ra < M ? ra : M - 1;
            int rb = n0 + r; rb = rb < N ? rb : N - 1;
            va[i] = *(const float4*)(A  + (size_t)ra * lda + k0 + sj * 4);
            vb[i] = *(const float4*)(Bm + (size_t)rb * ldb + k0 + sj * 4);
        }
        __syncthreads();
        #pragma unroll
        for (int i = 0; i < 4; i++) {
            int r = srow + i * 32;
            int swz = (r & 7) << 4;
            float aa[4] = {va[i].x, va[i].y, va[i].z, va[i].w};
            float bb[4] = {vb[i].x, vb[i].y, vb[i].z, vb[i].w};
            ushort4 ahv, alv, bhv, blv;
            {
                unsigned short h0 = f2bf(aa[0]), h1 = f2bf(aa[1]), h2 = f2bf(aa[2]), h3 = f2bf(aa[3]);
                ahv = make_ushort4(h0, h1, h2, h3);
                alv = make_ushort4(f2bf(aa[0] - bf2f(h0)), f2bf(aa[1] - bf2f(h1)),
                                   f2bf(aa[2] - bf2f(h2)), f2bf(aa[3] - bf2f(h3)));
                unsigned short g0 = f2bf(bb[0]), g1 = f2bf(bb[1]), g2 = f2bf(bb[2]), g3 = f2bf(bb[3]);
                bhv = make_ushort4(g0, g1, g2, g3);
                blv = make_ushort4(f2bf(bb[0] - bf2f(g0)), f2bf(bb[1] - bf2f(g1)),
                                   f2bf(bb[2] - bf2f(g2)), f2bf(bb[3] - bf2f(g3)));
            }
            int ohi = ((8 * sj) ^ swz) >> 1;
            int olo = ((64 + 8 * sj) ^ swz) >> 1;
            *(ushort4*)&Asl[r * 64 + ohi] = ahv;
            *(ushort4*)&Asl[r * 64 + olo] = alv;
            *(ushort4*)&Bsl[r * 64 + ohi] = bhv;
            *(ushort4*)&Bsl[r * 64 + olo] = blv;
        }
        __syncthreads();
        const int fr = lane & 15, kg = lane >> 4;
        bf16x8 ah[4], al[4], bh[4], bl[4];
        #pragma unroll
        for (int m = 0; m < 4; m++) {
            int r = wr * 64 + m * 16 + fr;
            int swz = (r & 7) << 4;
            const unsigned char* base = (const unsigned char*)&Asl[r * 64];
            ah[m] = *(const bf16x8*)(base + ((16 * kg) ^ swz));
            al[m] = *(const bf16x8*)(base + ((64 + 16 * kg) ^ swz));
        }
        #pragma unroll
        for (int n = 0; n < 4; n++) {
            int r = wc * 64 + n * 16 + fr;
            int swz = (r & 7) << 4;
            const unsigned char* base = (const unsigned char*)&Bsl[r * 64];
            bh[n] = *(const bf16x8*)(base + ((16 * kg) ^ swz));
            bl[n] = *(const bf16x8*)(base + ((64 + 16 * kg) ^ swz));
        }
        #pragma unroll
        for (int m = 0; m < 4; m++)
            #pragma unroll
            for (int n = 0; n < 4; n++) {
                acc[m][n] = __builtin_amdgcn_mfma_f32_16x16x32_bf16(ah[m], bh[n], acc[m][n], 0, 0, 0);
                acc[m][n] = __builtin_amdgcn_mfma_f32_16x16x32_bf16(ah[m], bl[n], acc[m][n], 0, 0, 0);
                acc[m][n] = __builtin_amdgcn_mfma_f32_16x16x32_bf16(al[m], bh[n], acc[m][n], 0, 0, 0);
            }
    }

    const int fr = lane & 15, fq = lane >> 4;
    #pragma unroll
    for (int m = 0; m < 4; m++) {
        #pragma unroll
        for (int rr = 0; rr < 4; rr++) {
            int row = m0 + wr * 64 + m * 16 + fq * 4 + rr;
            if (row >= M) continue;
            #pragma unroll
            for (int n = 0; n < 4; n++) {
                int col = n0 + wc * 64 + n * 16 + fr;
                if (col >= N) continue;
                float v = acc[m][n][rr];
                size_t ci = (size_t)row * ldc + col;
                if (EPI == 0) {
                    C[ci] = v + bias[col];
                } else if (EPI == 1) {
                    C[ci] = v + bias[col] + res[ci];
                } else if (EPI == 2) {
                    v += bias[col];
                    C[ci] = 0.5f * v * (1.0f + erff(v * 0.70710678118654752f));
                } else {
                    C[ci] = v;
                }
            }
        }
    }
}

// ---------------- MFMA flash attention (bf16x3-split, online softmax) ----------------
// grid: (ceil(SEQ/64), NHEADS, GB), 256 threads = 4 waves, each wave owns 16 q rows.
// Q in registers (hi/lo frags); K in LDS bf16 hi/lo swizzled; V transposed via
// fp32 LDS pass into swizzled Vt; P (probs) -> per-wave LDS bf16 hi/lo.
// All products keep hi*hi + hi*lo + lo*hi => fp32-equivalent accuracy.
__global__ __launch_bounds__(256) void attn_mfma(const float* __restrict__ qkv,
                                                 float* __restrict__ att) {
    const int b = blockIdx.z, h = blockIdx.y, q0 = blockIdx.x * 64;
    const int t = threadIdx.x;
    const int lane = t & 63, wid = t >> 6;
    const int fr = lane & 15, kg = lane >> 4;
    __shared__ unsigned short Khl[64 * 128];        // 16 KB: row k-tok: hi[64]|lo[64]
    __shared__ unsigned char SV[64 * 68 * 4];       // 17 KB: V32 fp32, later P per wave
    __shared__ unsigned short Vt[64 * 128];         // 16 KB: row d: hi[64 ktok]|lo[64]
    unsigned char* KhlB = (unsigned char*)Khl;
    float* V32 = (float*)SV;
    unsigned char* PwB = SV + wid * 4096;           // 16 rows x 256B per wave
    unsigned char* VtB = (unsigned char*)Vt;
    const size_t rowbase = (size_t)b * SEQ * (3 * CDIM);

    // ---- Q fragments (reused across all k-tiles) ----
    bf16x8 qh[2], qlo[2];
    {
        int qrow = q0 + wid * 16 + fr; qrow = qrow < SEQ ? qrow : SEQ - 1;
        const float* qbase = qkv + rowbase + (size_t)qrow * (3 * CDIM) + h * DHEAD;
        #pragma unroll
        for (int ds = 0; ds < 2; ds++) {
            float tmp[8];
            *(float4*)(tmp)     = *(const float4*)(qbase + ds * 32 + kg * 8);
            *(float4*)(tmp + 4) = *(const float4*)(qbase + ds * 32 + kg * 8 + 4);
            #pragma unroll
            for (int j = 0; j < 8; j++) {
                unsigned short hh = f2bf(tmp[j]);
                qh[ds][j]  = (short)hh;
                qlo[ds][j] = (short)f2bf(tmp[j] - bf2f(hh));
            }
        }
    }

    f32x4 acc_o[4];
    #pragma unroll
    for (int i = 0; i < 4; i++) { f32x4 z = {0.f,0.f,0.f,0.f}; acc_o[i] = z; }
    float m_run[4] = {-1e30f, -1e30f, -1e30f, -1e30f};
    float l_run[4] = {0.f, 0.f, 0.f, 0.f};

    const int srow = t >> 2;           // staging row 0..63
    const int sq   = t & 3;

    for (int c0 = 0; c0 < SEQ; c0 += 64) {
        // 1. global loads (K,V rows, clamped)
        float4 kv[4], vv[4];
        {
            int krow = c0 + srow; krow = krow < SEQ ? krow : SEQ - 1;
            const float* base = qkv + rowbase + (size_t)krow * (3 * CDIM) + h * DHEAD;
            #pragma unroll
            for (int i = 0; i < 4; i++) {
                int dchunk = sq * 16 + i * 4;
                kv[i] = *(const float4*)(base + CDIM + dchunk);
                vv[i] = *(const float4*)(base + 2 * CDIM + dchunk);
            }
        }
        __syncthreads();   // prev tile's LDS reads (K frags, Vt, P) complete
        // 2. write K (bf16 hi/lo, swizzled) and V32 (fp32)
        {
            int swz = (srow & 7) << 4;
            #pragma unroll
            for (int i = 0; i < 4; i++) {
                int dchunk = sq * 16 + i * 4;
                float a[4] = {kv[i].x, kv[i].y, kv[i].z, kv[i].w};
                unsigned short h0 = f2bf(a[0]), h1 = f2bf(a[1]), h2 = f2bf(a[2]), h3 = f2bf(a[3]);
                ushort4 hv = make_ushort4(h0, h1, h2, h3);
                ushort4 lv = make_ushort4(f2bf(a[0] - bf2f(h0)), f2bf(a[1] - bf2f(h1)),
                                          f2bf(a[2] - bf2f(h2)), f2bf(a[3] - bf2f(h3)));
                *(ushort4*)(KhlB + srow * 256 + ((dchunk * 2) ^ swz)) = hv;
                *(ushort4*)(KhlB + srow * 256 + 128 + ((dchunk * 2) ^ swz)) = lv;
                *(float4*)&V32[srow * 68 + dchunk] = vv[i];
            }
        }
        __syncthreads();   // staging visible
        // 3a. transpose V32 -> Vt (bf16 hi/lo, swizzled)
        {
            int d = t >> 2, k0b = (t & 3) * 16;
            unsigned short hb[16], lb[16];
            #pragma unroll
            for (int i = 0; i < 16; i++) {
                float v = V32[(k0b + i) * 68 + d];
                unsigned short hh = f2bf(v);
                hb[i] = hh; lb[i] = f2bf(v - bf2f(hh));
            }
            int swz = (d & 7) << 4;
            #pragma unroll
            for (int c = 0; c < 4; c++) {
                ushort4 hv = make_ushort4(hb[4*c], hb[4*c+1], hb[4*c+2], hb[4*c+3]);
                ushort4 lv = make_ushort4(lb[4*c], lb[4*c+1], lb[4*c+2], lb[4*c+3]);
                *(ushort4*)(VtB + d * 256 + (((k0b + 4 * c) * 2) ^ swz)) = hv;
                *(ushort4*)(VtB + d * 256 + 128 + (((k0b + 4 * c) * 2) ^ swz)) = lv;
            }
        }
        // 3b. QK^T: S[16 q][64 ktok] per wave
        f32x4 s[4];
        #pragma unroll
        for (int i = 0; i < 4; i++) { f32x4 z = {0.f,0.f,0.f,0.f}; s[i] = z; }
        #pragma unroll
        for (int ds = 0; ds < 2; ds++) {
            #pragma unroll
            for (int n = 0; n < 4; n++) {
                int r = n * 16 + fr;
                int swz = (r & 7) << 4;
                const unsigned char* rb = KhlB + r * 256;
                bf16x8 kh = *(const bf16x8*)(rb + ((ds * 64 + kg * 16) ^ swz));
                bf16x8 kl = *(const bf16x8*)(rb + 128 + ((ds * 64 + kg * 16) ^ swz));
                s[n] = __builtin_amdgcn_mfma_f32_16x16x32_bf16(qh[ds], kh, s[n], 0, 0, 0);
                s[n] = __builtin_amdgcn_mfma_f32_16x16x32_bf16(qh[ds], kl, s[n], 0, 0, 0);
                s[n] = __builtin_amdgcn_mfma_f32_16x16x32_bf16(qlo[ds], kh, s[n], 0, 0, 0);
            }
        }
        __syncthreads();   // Vt ready; K/V32 reads complete
        // 4. online softmax (C-layout: col=n*16+fr, row=(lane>>4)*4+r)
        float p[4][4];     // [n][r]
        #pragma unroll
        for (int n = 0; n < 4; n++) {
            int kcol = c0 + n * 16 + fr;
            #pragma unroll
            for (int r = 0; r < 4; r++) {
                float sv = s[n][r] * 0.125f;
                if (kcol >= SEQ) sv = -1e30f;
                p[n][r] = sv;
            }
        }
        float corr[4];
        #pragma unroll
        for (int r = 0; r < 4; r++) {
            float mx = fmaxf(fmaxf(p[0][r], p[1][r]), fmaxf(p[2][r], p[3][r]));
            mx = fmaxf(mx, __shfl_xor(mx, 1));
            mx = fmaxf(mx, __shfl_xor(mx, 2));
            mx = fmaxf(mx, __shfl_xor(mx, 4));
            mx = fmaxf(mx, __shfl_xor(mx, 8));
            float mnew = fmaxf(m_run[r], mx);
            corr[r] = __expf(m_run[r] - mnew);
            m_run[r] = mnew;
            float ls = 0.f;
            #pragma unroll
            for (int n = 0; n < 4; n++) {
                p[n][r] = __expf(p[n][r] - mnew);
                ls += p[n][r];
            }
            ls += __shfl_xor(ls, 1);
            ls += __shfl_xor(ls, 2);
            ls += __shfl_xor(ls, 4);
            ls += __shfl_xor(ls, 8);
            l_run[r] = l_run[r] * corr[r] + ls;
        }
        #pragma unroll
        for (int nd = 0; nd < 4; nd++)
            #pragma unroll
            for (int r = 0; r < 4; r++)
                acc_o[nd][r] *= corr[r];
        // 5. write P (bf16 hi/lo) to per-wave LDS
        {
            int qb = (lane >> 4) * 4;
            #pragma unroll
            for (int n = 0; n < 4; n++) {
                int kcol = n * 16 + fr;
                #pragma unroll
                for (int r = 0; r < 4; r++) {
                    int qq = qb + r;
                    unsigned short ph = f2bf(p[n][r]);
                    unsigned short pl = f2bf(p[n][r] - bf2f(ph));
                    int off = (kcol * 2) ^ ((qq & 7) << 4);
                    *(unsigned short*)(PwB + qq * 256 + off) = ph;
                    *(unsigned short*)(PwB + qq * 256 + 128 + off) = pl;
                }
            }
        }
        // 6. PV: O += P[16q x 64k] * V[64k x 64d]
        #pragma unroll
        for (int ks = 0; ks < 2; ks++) {
            int swzp = (fr & 7) << 4;
            bf16x8 pah = *(const bf16x8*)(PwB + fr * 256 + ((ks * 64 + kg * 16) ^ swzp));
            bf16x8 pal = *(const bf16x8*)(PwB + fr * 256 + 128 + ((ks * 64 + kg * 16) ^ swzp));
            #pragma unroll
            for (int nd = 0; nd < 4; nd++) {
                int rv = nd * 16 + fr;
                int swzv = (rv & 7) << 4;
                const unsigned char* rb = VtB + rv * 256;
                bf16x8 vh = *(const bf16x8*)(rb + ((ks * 64 + kg * 16) ^ swzv));
                bf16x8 vl = *(const bf16x8*)(rb + 128 + ((ks * 64 + kg * 16) ^ swzv));
                acc_o[nd] = __builtin_amdgcn_mfma_f32_16x16x32_bf16(pah, vh, acc_o[nd], 0, 0, 0);
                acc_o[nd] = __builtin_amdgcn_mfma_f32_16x16x32_bf16(pah, vl, acc_o[nd], 0, 0, 0);
                acc_o[nd] = __builtin_amdgcn_mfma_f32_16x16x32_bf16(pal, vh, acc_o[nd], 0, 0, 0);
            }
        }
    }
    // epilogue: O layout col(d)=nd*16+fr, row(q)=(lane>>4)*4+r
    #pragma unroll
    for (int r = 0; r < 4; r++) {
        int q = q0 + wid * 16 + (lane >> 4) * 4 + r;
        if (q >= SEQ) continue;
        float inv = 1.f / l_run[r];
        float* o = att + ((size_t)b * SEQ + q) * CDIM + h * DHEAD;
        #pragma unroll
        for (int nd = 0; nd < 4; nd++)
            o[nd * 16 + fr] = acc_o[nd][r] * inv;
    }
}

// ---------------- normalize img tokens ----------------
__global__ __launch_bounds__(256) void xn_kernel(const float* __restrict__ x2,
                                                 float* __restrict__ xn) {
    __shared__ float red[4];
    int tok = blockIdx.x;
    int b = tok / NIMG, n = tok % NIMG;
    const float* xr = x2 + ((size_t)b * SEQ + 1 + n) * CDIM;
    float* onr = xn + (size_t)tok * CDIM;
    int t = threadIdx.x;
    float v0 = xr[t], v1 = xr[t + 256], v2 = xr[t + 512];
    float ss = blk_sum256(v0 * v0 + v1 * v1 + v2 * v2, red);
    float nrm = fmaxf(sqrtf(ss), 1e-12f);
    float inv = 1.f / nrm;
    onr[t] = v0 * inv; onr[t + 256] = v1 * inv; onr[t + 512] = v2 * inv;
}

// ---------------- row max of symmetrized sim (excluding diagonal) ----------------
__global__ __launch_bounds__(64) void rowmax_kernel(const float* __restrict__ sim,
                                                    float* __restrict__ ms) {
    int row = blockIdx.x;
    int b = row / NIMG, n = row % NIMG;
    const float* sb = sim + (size_t)b * NIMG * NIMG;
    int lane = threadIdx.x;
    float mx = -1e30f;
    #pragma unroll
    for (int i = 0; i < NIMG / 64; i++) {
        int m = lane + i * 64;
        if (m != n) {
            float v = 0.5f * (sb[(size_t)n * NIMG + m] + sb[(size_t)m * NIMG + n]);
            mx = fmaxf(mx, v);
        }
    }
    #pragma unroll
    for (int o = 32; o; o >>= 1) mx = fmaxf(mx, __shfl_down(mx, o));
    if (lane == 0) ms[row] = mx;
}

// ---------------- exact top-k selection with lax.top_k tie semantics ----------------
__global__ __launch_bounds__(576) void select_kernel(const float* __restrict__ ms,
        int* __restrict__ mergemask, int* __restrict__ keeppos) {
    __shared__ float v[NIMG];
    __shared__ int keepf[NIMG];
    int b = blockIdx.x;
    int n = threadIdx.x;
    v[n] = ms[b * NIMG + n];
    __syncthreads();
    float vn = v[n];
    int rank_desc = 0, rank_asc = 0;
    for (int m = 0; m < NIMG; m++) {
        float vm = v[m];
        int tie_lo = (vm == vn && m < n);
        rank_desc += (vm > vn) || tie_lo;
        rank_asc  += (vm < vn) || tie_lo;
    }
    int merge = rank_desc < NMERGE;
    int keep  = rank_asc  < NMERGE;
    mergemask[b * NIMG + n] = merge;
    keepf[n] = keep;
    __syncthreads();
    if (keep) {
        int pos = 0;
        for (int m = 0; m < n; m++) pos += keepf[m];
        keeppos[b * NIMG + n] = pos;
    } else {
        keeppos[b * NIMG + n] = -1;
    }
}

// ---------------- average of merged tokens ----------------
__global__ __launch_bounds__(256) void avg_kernel(const float* __restrict__ x2,
        const int* __restrict__ mask, float* __restrict__ avg) {
    int b = blockIdx.x;
    int t = threadIdx.x;
    #pragma unroll
    for (int cc = 0; cc < 3; cc++) {
        int c = t + cc * 256;
        float s = 0.f;
        for (int n = 0; n < NIMG; n++)
            if (mask[b * NIMG + n]) s += x2[((size_t)b * SEQ + 1 + n) * CDIM + c];
        avg[b * CDIM + c] = (s / (float)NMERGE) / (float)(NIMG - NMERGE);
    }
}

// ---------------- assemble output ----------------
__global__ __launch_bounds__(192) void assemble_kernel(const float* __restrict__ x2,
        const int* __restrict__ keeppos, const float* __restrict__ avg,
        float* __restrict__ out) {
    int g = blockIdx.x;
    int b = g / SEQ, s_ = g % SEQ;
    int t = threadIdx.x;
    const float4* src = (const float4*)(x2 + (size_t)g * CDIM);
    if (s_ == 0) {
        float4* dst = (float4*)(out + (size_t)b * 289 * CDIM);
        dst[t] = src[t];
    } else {
        int n = s_ - 1;
        int pos = keeppos[b * NIMG + n];
        if (pos < 0) return;
        const float4* av = (const float4*)(avg + (size_t)b * CDIM);
        float4 v = src[t], a = av[t];
        v.x += a.x; v.y += a.y; v.z += a.z; v.w += a.w;
        float4* dst = (float4*)(out + ((size_t)b * 289 + 1 + pos) * CDIM);
        dst[t] = v;
    }
}

extern "C" void kernel_launch(void* const* d_in, const int* in_sizes, int n_in,
                              void* d_out, int out_size, void* d_ws, size_t ws_size,
                              hipStream_t stream) {
    const float* x      = (const float*)d_in[0];
    const float* qkv_w  = (const float*)d_in[1];
    const float* qkv_b  = (const float*)d_in[2];
    const float* proj_w = (const float*)d_in[3];
    const float* proj_b = (const float*)d_in[4];
    const float* ln1_g  = (const float*)d_in[5];
    const float* ln1_b  = (const float*)d_in[6];
    const float* ln2_g  = (const float*)d_in[7];
    const float* ln2_b  = (const float*)d_in[8];
    const float* fc1_w  = (const float*)d_in[9];
    const float* fc1_b  = (const float*)d_in[10];
    const float* fc2_w  = (const float*)d_in[11];
    const float* fc2_b  = (const float*)d_in[12];

    if (ws_size < NEED_BYTES) return;

    float* ws   = (float*)d_ws;
    float* bh   = ws + O_BH;
    float* ba   = ws + O_BA;
    float* bq   = ws + O_BQ;
    float* ms   = ws + O_MS;
    int*   mask = (int*)(ws + O_MASK);
    int*   pos  = (int*)(ws + O_POS);
    float* avg  = ws + O_AVG;
    float* outp = (float*)d_out;

    // 1. h = LN1(x)
    ln_kernel<<<MTOK, 256, 0, stream>>>(x, ln1_g, ln1_b, bh);

    // 2. per-group qkv GEMM + MFMA attention
    for (int g = 0; g < NGROUP; g++) {
        const float* hg = bh + (size_t)g * MGRP * CDIM;
        float* attg = ba + (size_t)g * MGRP * CDIM;
        gemm_mfma<0><<<dim3((MGRP + 127) / 128, 18, 1), 256, 0, stream>>>(
            hg, 0, CDIM, qkv_w, 0, CDIM, bq, 0, 3 * CDIM, qkv_b, nullptr,
            MGRP, 3 * CDIM, CDIM);
        attn_mfma<<<dim3((SEQ + 63) / 64, NHEADS, GB), 256, 0, stream>>>(bq, attg);
    }

    // 3. x1 = x + att @ proj_w^T + proj_b
    gemm_mfma<1><<<dim3((MTOK + 127) / 128, 6, 1), 256, 0, stream>>>(
        ba, 0, CDIM, proj_w, 0, CDIM, bh, 0, CDIM, proj_b, x, MTOK, CDIM, CDIM);

    // 4. h2 = LN2(x1)
    ln_kernel<<<MTOK, 256, 0, stream>>>(bh, ln2_g, ln2_b, ba);

    // 5. MLP in M-chunks
    for (int c0 = 0; c0 < MTOK; c0 += MLPCH) {
        int mc = (MTOK - c0 < MLPCH) ? (MTOK - c0) : MLPCH;
        const float* h2c = ba + (size_t)c0 * CDIM;
        float* x1c = bh + (size_t)c0 * CDIM;
        gemm_mfma<2><<<dim3((mc + 127) / 128, 24, 1), 256, 0, stream>>>(
            h2c, 0, CDIM, fc1_w, 0, CDIM, bq, 0, 3072, fc1_b, nullptr,
            mc, 3072, CDIM);
        gemm_mfma<1><<<dim3((mc + 127) / 128, 6, 1), 256, 0, stream>>>(
            bq, 0, 3072, fc2_w, 0, 3072, x1c, 0, CDIM, fc2_b, x1c,
            mc, CDIM, 3072);
    }

    // 6. normalize img tokens
    xn_kernel<<<NBATCH * NIMG, 256, 0, stream>>>(bh, ba);

    // 7. sim = xn @ xn^T per batch
    gemm_mfma<3><<<dim3(5, 5, NBATCH), 256, 0, stream>>>(
        ba, (long long)NIMG * CDIM, CDIM, ba, (long long)NIMG * CDIM, CDIM,
        bq, (long long)NIMG * NIMG, NIMG, nullptr, nullptr, NIMG, NIMG, CDIM);

    // 8. row max of symmetrized sim
    rowmax_kernel<<<NBATCH * NIMG, 64, 0, stream>>>(bq, ms);
    // 9. top-k selection
    select_kernel<<<NBATCH, NIMG, 0, stream>>>(ms, mask, pos);
    // 10. merged-token average
    avg_kernel<<<NBATCH, 256, 0, stream>>>(bh, mask, avg);
    // 11. assemble output
    assemble_kernel<<<MTOK, 192, 0, stream>>>(bh, pos, avg, outp);
}